// Round 1
// 551.310 us; speedup vs baseline: 1.0329x; 1.0329x over previous
//
#include <hip/hip_runtime.h>
#include <hip/hip_bf16.h>
#include <stdint.h>

#define B_   32
#define S_   4096
#define HID_ 5120
#define H_   16
#define DN_  128
#define DR_  64
#define DV_  128
#define QL_  1536
#define KL_  512
#define KC_  576            // KL + DR
#define NQKV_ 2112          // QL + KL + DR
#define NQB_  3072          // H*(DN+DR)
#define EPS_ 1e-6f
#define SCALE_ 0.07216878364870323f   // (DN+DR)^-0.5

typedef __attribute__((ext_vector_type(4))) float f32x4;
typedef __attribute__((ext_vector_type(8))) short s16x8;
typedef __attribute__((ext_vector_type(2))) unsigned int u32x2;
typedef __attribute__((ext_vector_type(4))) unsigned int u32x4;

// Native bf16 conversion (RNE) — compiler pairs these into v_cvt_pk_bf16_f32.
__device__ __forceinline__ unsigned short bf(float f) {
  union { __hip_bfloat16 h; unsigned short u; } v;
  v.h = __float2bfloat16(f);
  return v.u;
}
__device__ __forceinline__ unsigned int bf2(float x, float y) {
  union { __hip_bfloat162 h; unsigned int u; } v;
  v.h = __float22bfloat162_rn(float2{x, y});
  return v.u;
}
__device__ __forceinline__ s16x8 pack8(const float* w) {
  union { u32x4 q; s16x8 s; } v;
  v.q = (u32x4){bf2(w[0], w[1]), bf2(w[2], w[3]), bf2(w[4], w[5]), bf2(w[6], w[7])};
  return v.s;
}

// ------------- MFMA split-K GEMM (bf16 A): P[ks][b][n] = sum_{k in slice} A[b][k]*W[k][n]
template<int K, int TK, int N>
__global__ __launch_bounds__(256) void gemm_bf(const unsigned short* __restrict__ Abf,
                                               const float* __restrict__ W,
                                               float* __restrict__ P) {
  int t = threadIdx.x, wave = t >> 6, lane = t & 63;
  int quad = lane >> 4, lo = lane & 15;
  int n0 = blockIdx.x * 64 + wave * 16;
  int k0 = blockIdx.y * TK;
  f32x4 acc0 = {0.f, 0.f, 0.f, 0.f}, acc1 = {0.f, 0.f, 0.f, 0.f};
  const float* wp = W + (size_t)(k0 + quad * 8) * N + n0 + lo;
  const unsigned short* a0p = Abf + (size_t)lo * K + k0 + quad * 8;
  const unsigned short* a1p = Abf + (size_t)(16 + lo) * K + k0 + quad * 8;
#pragma unroll 2
  for (int kk = 0; kk < TK / 32; ++kk) {
    s16x8 a0 = *(const s16x8*)(a0p + kk * 32);
    s16x8 a1 = *(const s16x8*)(a1p + kk * 32);
    float wv[8];
#pragma unroll
    for (int j = 0; j < 8; ++j) wv[j] = wp[((size_t)kk * 32 + j) * N];
    s16x8 bfv = pack8(wv);
    acc0 = __builtin_amdgcn_mfma_f32_16x16x32_bf16(a0, bfv, acc0, 0, 0, 0);
    acc1 = __builtin_amdgcn_mfma_f32_16x16x32_bf16(a1, bfv, acc1, 0, 0, 0);
  }
  float* p = P + ((size_t)blockIdx.y * B_) * N + n0 + lo;
#pragma unroll
  for (int reg = 0; reg < 4; ++reg) {
    p[(size_t)(quad * 4 + reg) * N]      = acc0[reg];
    p[(size_t)(16 + quad * 4 + reg) * N] = acc1[reg];
  }
}

// ------------- same, but A is fp32 (fused cvt for the first GEMM)
template<int K, int TK, int N>
__global__ __launch_bounds__(256) void gemm_f32a(const float* __restrict__ A,
                                                 const float* __restrict__ W,
                                                 float* __restrict__ P) {
  int t = threadIdx.x, wave = t >> 6, lane = t & 63;
  int quad = lane >> 4, lo = lane & 15;
  int n0 = blockIdx.x * 64 + wave * 16;
  int k0 = blockIdx.y * TK;
  f32x4 acc0 = {0.f, 0.f, 0.f, 0.f}, acc1 = {0.f, 0.f, 0.f, 0.f};
  const float* wp = W + (size_t)(k0 + quad * 8) * N + n0 + lo;
  const float* a0p = A + (size_t)lo * K + k0 + quad * 8;
  const float* a1p = A + (size_t)(16 + lo) * K + k0 + quad * 8;
#pragma unroll 2
  for (int kk = 0; kk < TK / 32; ++kk) {
    f32x4 x0 = *(const f32x4*)(a0p + kk * 32);
    f32x4 x1 = *(const f32x4*)(a0p + kk * 32 + 4);
    f32x4 y0 = *(const f32x4*)(a1p + kk * 32);
    f32x4 y1 = *(const f32x4*)(a1p + kk * 32 + 4);
    float a0f[8], a1f[8];
#pragma unroll
    for (int j = 0; j < 4; ++j) {
      a0f[j] = x0[j]; a0f[4 + j] = x1[j];
      a1f[j] = y0[j]; a1f[4 + j] = y1[j];
    }
    s16x8 a0 = pack8(a0f);
    s16x8 a1 = pack8(a1f);
    float wv[8];
#pragma unroll
    for (int j = 0; j < 8; ++j) wv[j] = wp[((size_t)kk * 32 + j) * N];
    s16x8 bfv = pack8(wv);
    acc0 = __builtin_amdgcn_mfma_f32_16x16x32_bf16(a0, bfv, acc0, 0, 0, 0);
    acc1 = __builtin_amdgcn_mfma_f32_16x16x32_bf16(a1, bfv, acc1, 0, 0, 0);
  }
  float* p = P + ((size_t)blockIdx.y * B_) * N + n0 + lo;
#pragma unroll
  for (int reg = 0; reg < 4; ++reg) {
    p[(size_t)(quad * 4 + reg) * N]      = acc0[reg];
    p[(size_t)(16 + quad * 4 + reg) * N] = acc1[reg];
  }
}

#define NSL1 32   // k-slices of gemm1
#define NSL2 24   // k-slices of gemm2
#define NSL3 16   // k-slices of gemm3

// ---------------- k2a: sum k-slices, rmsnorms, rope(k_pe). grid (2, B): x=0 Q-part, x=1 KV-part
__global__ __launch_bounds__(256) void k2a(const float* __restrict__ P1, const float* __restrict__ qw,
                    const float* __restrict__ kvw, const int* __restrict__ pos,
                    unsigned short* __restrict__ qn_bf, float* __restrict__ latent_n,
                    float* __restrict__ kpe_rot, float* __restrict__ cs_buf) {
  int b = blockIdx.y, t = threadIdx.x;
  __shared__ float row[QL_];
  __shared__ float red[256];
  if (blockIdx.x == 0) {
    float sq = 0.f;
    for (int n = t; n < QL_; n += 256) {
      float s = 0.f;
#pragma unroll
      for (int ks = 0; ks < NSL1; ++ks) s += P1[((size_t)ks * B_ + b) * NQKV_ + n];
      row[n] = s; sq += s * s;
    }
    red[t] = sq;
    __syncthreads();
    for (int off = 128; off > 0; off >>= 1) {
      if (t < off) red[t] += red[t + off];
      __syncthreads();
    }
    float rq = 1.0f / sqrtf(red[0] / QL_ + EPS_);
    for (int n = t; n < QL_; n += 256) qn_bf[(size_t)b * QL_ + n] = bf(row[n] * rq * qw[n]);
  } else {
    float sl = 0.f;
    for (int n = t; n < KL_ + DR_; n += 256) {
      float s = 0.f;
#pragma unroll
      for (int ks = 0; ks < NSL1; ++ks) s += P1[((size_t)ks * B_ + b) * NQKV_ + QL_ + n];
      row[n] = s;
      if (n < KL_) sl += s * s;
    }
    red[t] = sl;
    __syncthreads();
    for (int off = 128; off > 0; off >>= 1) {
      if (t < off) red[t] += red[t + off];
      __syncthreads();
    }
    float rl = 1.0f / sqrtf(red[0] / KL_ + EPS_);
    for (int n = t; n < KL_; n += 256) latent_n[(size_t)b * KL_ + n] = row[n] * rl * kvw[n];
    if (t < 32) {
      double inv = exp(-((double)t / 32.0) * log(10000.0));
      float fr = (float)pos[b] * (float)inv;
      float c = (float)cos((double)fr), s = (float)sin((double)fr);
      cs_buf[(b * 32 + t) * 2] = c; cs_buf[(b * 32 + t) * 2 + 1] = s;
      float x1 = row[KL_ + 2 * t], x2 = row[KL_ + 2 * t + 1];
      kpe_rot[b * DR_ + 2 * t]     = x1 * c - x2 * s;
      kpe_rot[b * DR_ + 2 * t + 1] = x2 * c + x1 * s;
    }
  }
}

// ---------------- k2c: sum k-slices, rope(q_pe), q_abs = q_nope @ w_kc ----------------
// grid (8, B): block handles 2 heads; 2 waves per head split the 512 output cols.
__global__ __launch_bounds__(256) void k2c(const float* __restrict__ P2,
                                           const float* __restrict__ w_kc,
                                           const float* __restrict__ cs_buf,
                                           unsigned short* __restrict__ q_cat) {
  int b = blockIdx.y, t = threadIdx.x, wave = t >> 6, lane = t & 63;
  int hl = blockIdx.x * 2;
  __shared__ float qh[2][192];
  for (int j = t; j < 384; j += 256) {
    int hh = j / 192, jj = j - hh * 192;
    float s = 0.f;
    int col = (hl + hh) * 192 + jj;
#pragma unroll
    for (int ks = 0; ks < NSL2; ++ks) s += P2[((size_t)ks * B_ + b) * NQB_ + col];
    qh[hh][jj] = s;
  }
  __syncthreads();
  if (t < 64) {
    int hh = t >> 5, ll = t & 31;
    float c = cs_buf[(b * 32 + ll) * 2], s = cs_buf[(b * 32 + ll) * 2 + 1];
    float x1 = qh[hh][DN_ + 2 * ll], x2 = qh[hh][DN_ + 2 * ll + 1];
    qh[hh][DN_ + 2 * ll]     = x1 * c - x2 * s;
    qh[hh][DN_ + 2 * ll + 1] = x2 * c + x1 * s;
  }
  __syncthreads();
  int hh = wave >> 1, half = wave & 1;
  int h = hl + hh;
  float acc[4] = {0.f, 0.f, 0.f, 0.f};
  const float* wk = w_kc + (size_t)h * DN_ * KL_ + half * 256;
#pragma unroll 2
  for (int d = 0; d < DN_; ++d) {
    float qd = qh[hh][d];
#pragma unroll
    for (int i = 0; i < 4; ++i)
      acc[i] = fmaf(qd, wk[(size_t)d * KL_ + lane + 64 * i], acc[i]);
  }
  unsigned short* qc = q_cat + ((size_t)b * H_ + h) * KC_;
#pragma unroll
  for (int i = 0; i < 4; ++i) qc[half * 256 + lane + 64 * i] = bf(acc[i] * SCALE_);
  if (half == 0) qc[KL_ + lane] = bf(qh[hh][DN_ + lane] * SCALE_);
}

// ---------------- attn: flash attention (bf16 MFMA, online softmax) ----------------
#define LP_ 584          // LDS row pitch (bf16): 16B-aligned rows
#define CHUNK_ 256
#define TR_ 32
#define NTL_ 8

__global__ __launch_bounds__(256, 2) void attn(
    const float* __restrict__ cache_l, const float* __restrict__ cache_r,
    const float* __restrict__ latent_n, const float* __restrict__ kpe_rot,
    const unsigned short* __restrict__ q_cat,
    float* __restrict__ ws_acc, float* __restrict__ ws_ml) {
  int chunk = blockIdx.x, b = blockIdx.y;
  int t = threadIdx.x, wave = t >> 6, lane = t & 63;
  int quad = lane >> 4, lo = lane & 15;

  __shared__ __attribute__((aligned(16))) unsigned short Lt[TR_ * LP_];
  __shared__ __attribute__((aligned(16))) unsigned short pb[4][H_ * TR_];

  s16x8 af[18];
  const unsigned short* qc = q_cat + ((size_t)b * H_ + lo) * KC_;
#pragma unroll
  for (int ks = 0; ks < 18; ++ks) af[ks] = *(const s16x8*)(qc + ks * 32 + quad * 8);

  f32x4 accc[NTL_];
#pragma unroll
  for (int i = 0; i < NTL_; ++i) accc[i] = (f32x4){0.f, 0.f, 0.f, 0.f};
  float m_run[4], l_run[4];
#pragma unroll
  for (int r = 0; r < 4; ++r) { m_run[r] = -3.0e38f; l_run[r] = 0.f; }

  int r8 = t >> 3, u = t & 7;

  float4 v[18];
  auto load_tile = [&](int tile) {
    int s = chunk * CHUNK_ + tile * TR_ + r8;
    const float* rl = cache_l + ((size_t)b * S_ + s) * KL_;
    const float* rr = cache_r + ((size_t)b * S_ + s) * DR_;
    if (s == S_ - 1) { rl = latent_n + (size_t)b * KL_; rr = kpe_rot + (size_t)b * DR_; }
#pragma unroll
    for (int j = 0; j < 18; ++j) {
      int c = u * 4 + j * 32;
      v[j] = *(const float4*)((j < 16) ? (rl + c) : (rr + (c - 512)));
    }
  };
  load_tile(0);

#pragma unroll 1
  for (int tile = 0; tile < NTL_; ++tile) {
    __syncthreads();
#pragma unroll
    for (int j = 0; j < 18; ++j) {
      int c = u * 4 + j * 32;
      u32x2 o; o[0] = bf2(v[j].x, v[j].y); o[1] = bf2(v[j].z, v[j].w);
      *(u32x2*)(&Lt[r8 * LP_ + c]) = o;
    }
    if (tile + 1 < NTL_) load_tile(tile + 1);
    __syncthreads();
    f32x4 sc0 = {0.f, 0.f, 0.f, 0.f}, sc1 = {0.f, 0.f, 0.f, 0.f};
#pragma unroll
    for (int ks = 0; ks < 18; ++ks) {
      s16x8 b0 = *(const s16x8*)(&Lt[lo * LP_ + ks * 32 + quad * 8]);
      s16x8 b1 = *(const s16x8*)(&Lt[(16 + lo) * LP_ + ks * 32 + quad * 8]);
      sc0 = __builtin_amdgcn_mfma_f32_16x16x32_bf16(af[ks], b0, sc0, 0, 0, 0);
      sc1 = __builtin_amdgcn_mfma_f32_16x16x32_bf16(af[ks], b1, sc1, 0, 0, 0);
    }
#pragma unroll
    for (int reg = 0; reg < 4; ++reg) {
      float s0 = sc0[reg], s1 = sc1[reg];
      float mt = fmaxf(s0, s1);
#pragma unroll
      for (int m = 1; m < 16; m <<= 1) mt = fmaxf(mt, __shfl_xor(mt, m, 64));
      float mn = fmaxf(m_run[reg], mt);
      float alpha = __expf(m_run[reg] - mn);
      m_run[reg] = mn;
      float p0 = __expf(s0 - mn), p1 = __expf(s1 - mn);
      float lt = p0 + p1;
#pragma unroll
      for (int m = 1; m < 16; m <<= 1) lt += __shfl_xor(lt, m, 64);
      l_run[reg] = l_run[reg] * alpha + lt;
#pragma unroll
      for (int i = 0; i < NTL_; ++i) accc[i][reg] *= alpha;
      int h = quad * 4 + reg;
      pb[wave][h * TR_ + lo]      = bf(p0);
      pb[wave][h * TR_ + 16 + lo] = bf(p1);
    }
    s16x8 ap = *(const s16x8*)(&pb[wave][lo * TR_ + quad * 8]);
#pragma unroll
    for (int nt = 0; nt < NTL_; ++nt) {
      int c = wave * 128 + nt * 16 + lo;
      s16x8 bv;
#pragma unroll
      for (int j = 0; j < 8; ++j) bv[j] = (short)Lt[(quad * 8 + j) * LP_ + c];
      accc[nt] = __builtin_amdgcn_mfma_f32_16x16x32_bf16(ap, bv, accc[nt], 0, 0, 0);
    }
  }
  float* accp = ws_acc + (((size_t)b * 16 + chunk) * H_) * KL_;
#pragma unroll
  for (int nt = 0; nt < NTL_; ++nt) {
    int c = wave * 128 + nt * 16 + lo;
#pragma unroll
    for (int reg = 0; reg < 4; ++reg)
      accp[(size_t)(quad * 4 + reg) * KL_ + c] = accc[nt][reg];
  }
  if (wave == 0 && lo == 0) {
#pragma unroll
    for (int reg = 0; reg < 4; ++reg) {
      int h = quad * 4 + reg;
      ws_ml[(((size_t)b * 16 + chunk) * H_ + h) * 2 + 0] = m_run[reg];
      ws_ml[(((size_t)b * 16 + chunk) * H_ + h) * 2 + 1] = l_run[reg];
    }
  }
}

// ---------------- combine chunks + ctx @ w_vc ----------------
__global__ __launch_bounds__(256) void combine(const float* __restrict__ ws_acc,
                        const float* __restrict__ ws_ml,
                        const float* __restrict__ w_vc, unsigned short* __restrict__ o_v) {
  int h = blockIdx.x, b = blockIdx.y, t = threadIdx.x;
  __shared__ float sm[16], sl[16];
  __shared__ float ctx[KL_];
  __shared__ float ps[256];
  if (t < 16) {
    sm[t] = ws_ml[(((size_t)b * 16 + t) * H_ + h) * 2];
    sl[t] = ws_ml[(((size_t)b * 16 + t) * H_ + h) * 2 + 1];
  }
  __syncthreads();
  float M = -3e38f;
#pragma unroll
  for (int i = 0; i < 16; ++i) M = fmaxf(M, sm[i]);
  float wkk[16]; float Lsum = 0.f;
#pragma unroll
  for (int i = 0; i < 16; ++i) { wkk[i] = __expf(sm[i] - M); Lsum += wkk[i] * sl[i]; }
  float invL = 1.0f / Lsum;
  for (int c = t; c < KL_; c += 256) {
    float s = 0.f;
#pragma unroll
    for (int i = 0; i < 16; ++i)
      s += wkk[i] * ws_acc[(((size_t)b * 16 + i) * H_ + h) * KL_ + c];
    ctx[c] = s * invL;
  }
  __syncthreads();
  int vv = t & 127, half = t >> 7;
  const float* wv = w_vc + (size_t)h * KL_ * DV_;
  float s0 = 0.f, s1 = 0.f;
#pragma unroll 4
  for (int k = half * 256; k < half * 256 + 256; k += 2) {
    s0 = fmaf(ctx[k],     wv[(size_t)k * DV_ + vv],       s0);
    s1 = fmaf(ctx[k + 1], wv[(size_t)(k + 1) * DV_ + vv], s1);
  }
  ps[t] = s0 + s1;
  __syncthreads();
  if (t < 128) o_v[(size_t)b * (H_ * DV_) + h * DV_ + t] = bf(ps[t] + ps[t + 128]);
}

// ---------------- reduce_out: sum k-slices of out projection (float4) ----------------
__global__ __launch_bounds__(256) void reduce_out(const float* __restrict__ P, float* __restrict__ out) {
  int i = blockIdx.x * 256 + threadIdx.x;   // 32*5120/4 = 40960 float4
  const f32x4* P4 = (const f32x4*)P;
  f32x4 s = P4[i];
#pragma unroll
  for (int ks = 1; ks < NSL3; ++ks) s += P4[(size_t)ks * 40960 + i];
  ((f32x4*)out)[i] = s;
}

extern "C" void kernel_launch(void* const* d_in, const int* in_sizes, int n_in,
                              void* d_out, int out_size, void* d_ws, size_t ws_size,
                              hipStream_t stream) {
  const float* hs    = (const float*)d_in[0];
  const int*   pos   = (const int*)d_in[1];
  const float* cl    = (const float*)d_in[2];
  const float* cr    = (const float*)d_in[3];
  const float* w_qkv = (const float*)d_in[4];
  const float* qnw   = (const float*)d_in[5];
  const float* w_qb  = (const float*)d_in[6];
  const float* kvnw  = (const float*)d_in[7];
  const float* w_kc  = (const float*)d_in[8];
  const float* w_vc  = (const float*)d_in[9];
  const float* w_o   = (const float*)d_in[10];
  float* out = (float*)d_out;

  char* ws = (char*)d_ws;
  float* ws_acc = (float*)(ws);                              // 16,777,216
  float* P1     = (float*)(ws + 16777216);                   // 32 x 32 x 2112 x4 = 8,650,752
  float* P2     = (float*)(ws + 25427968);                   // 24 x 32 x 3072 x4 = 9,437,184
  float* P5     = (float*)(ws + 34865152);                   // 16 x 32 x 5120 x4 = 10,485,760
  unsigned short* qn_bf = (unsigned short*)(ws + 45350912);  // 98,304
  float* latent_n = (float*)(ws + 45449216);                 // 65,536
  float* kpe_rot  = (float*)(ws + 45514752);                 // 8,192
  float* cs_buf   = (float*)(ws + 45522944);                 // 8,192
  unsigned short* q_cat = (unsigned short*)(ws + 45531136);  // 589,824
  float* ws_ml    = (float*)(ws + 46120960);                 // 65,536
  unsigned short* o_v_bf = (unsigned short*)(ws + 46186496); // 131,072

  gemm_f32a<HID_, 160, NQKV_><<<dim3(33, 32), 256, 0, stream>>>(hs, w_qkv, P1);
  k2a<<<dim3(2, 32), 256, 0, stream>>>(P1, qnw, kvnw, pos, qn_bf, latent_n, kpe_rot, cs_buf);
  gemm_bf<QL_, 64, NQB_><<<dim3(48, 24), 256, 0, stream>>>(qn_bf, w_qb, P2);
  k2c<<<dim3(8, 32), 256, 0, stream>>>(P2, w_kc, cs_buf, q_cat);
  attn<<<dim3(16, 32), 256, 0, stream>>>(cl, cr, latent_n, kpe_rot, q_cat, ws_acc, ws_ml);
  combine<<<dim3(16, 32), 256, 0, stream>>>(ws_acc, ws_ml, w_vc, o_v_bf);
  gemm_bf<H_ * DV_, 128, HID_><<<dim3(80, 16), 256, 0, stream>>>(o_v_bf, w_o, P5);
  reduce_out<<<160, 256, 0, stream>>>(P5, out);
}